// Round 14
// baseline (336.315 us; speedup 1.0000x reference)
//
#include <hip/hip_runtime.h>

typedef __attribute__((ext_vector_type(8))) short short8;
typedef __attribute__((ext_vector_type(4))) short short4v;
typedef __attribute__((ext_vector_type(4))) float f32x4;

#define B_  4
#define T_  2048
#define D_  1024
#define H_  16
#define HD_ 64

#define LOG2E 1.4426950408889634f
#define QSCALE 0.1803368801111243f   /* 0.125 * log2(e) */

__device__ __forceinline__ short f2bf(float f) {
  unsigned u = __builtin_bit_cast(unsigned, f);
  u = (u + 0x7FFFu + ((u >> 16) & 1u)) >> 16;
  return (short)u;
}
__device__ __forceinline__ short f2bf_trunc(float f) {   // 1-op pack for P (err <0.4%, biased low)
  return (short)(__builtin_bit_cast(unsigned, f) >> 16);
}
__device__ __forceinline__ float bf2f(short s) {
  unsigned u = ((unsigned)(unsigned short)s) << 16;
  return __builtin_bit_cast(float, u);
}

// async global->LDS, 16B per lane. lds ptr must be wave-uniform; HW adds lane*16.
__device__ __forceinline__ void g2l16(const void* g, void* l) {
  __builtin_amdgcn_global_load_lds((const __attribute__((address_space(1))) void*)g,
                                   (__attribute__((address_space(3))) void*)l, 16, 0, 0);
}

// ---------------- fused prep: x cast (blocks 0..4095) + bias->PB (blocks 4096..4639) ----
__global__ __launch_bounds__(512) void prep_kernel(const float* __restrict__ x,
                                                   short* __restrict__ xb,
                                                   const float* __restrict__ bias,
                                                   short* __restrict__ PB) {
  int bid = blockIdx.x;
  if (bid < 4096) {
    int i = (bid * 512 + threadIdx.x) * 4;
    float4 v = *(const float4*)(x + i);
    short4v o;
    o.x = f2bf(v.x); o.y = f2bf(v.y); o.z = f2bf(v.z); o.w = f2bf(v.w);
    *(short4v*)(xb + i) = o;
    return;
  }
  bid -= 4096;                     // 0..543
  int b = bid / 136, tidx = bid % 136;
  int qt = 0, base = 0;
  while (base + qt + 1 <= tidx) { base += qt + 1; ++qt; }
  int kt = tidx - base;
  int tid = threadIdx.x;
  int w = tid >> 6, lane = tid & 63, quad = lane >> 4, l15 = lane & 15;
  short vals[32];
#pragma unroll
  for (int tj = 0; tj < 8; ++tj)
#pragma unroll
    for (int rr = 0; rr < 4; ++rr) {
      int ql = w * 16 + quad * 4 + rr;
      int kl = tj * 16 + l15;
      float v = bias[((size_t)b * T_ + qt * 128 + ql) * T_ + kt * 128 + kl] * LOG2E;
      if (kt == qt && kl > ql) v = -1.0e9f;
      vals[tj * 4 + rr] = f2bf(v);
    }
  short* dst = PB + ((size_t)bid * 512 + tid) * 32;
#pragma unroll
  for (int j = 0; j < 4; ++j) *(short8*)(dst + j * 8) = *(const short8*)(vals + j * 8);
}

// ---------------- transpose-cast fp32 [R][C] -> bf16 [C][R], both weights fused ----
__device__ __forceinline__ void tcast_body(const float* __restrict__ src,
                                           short* __restrict__ dst, int R, int C,
                                           int cb, int rb, float tile[32][33]) {
  int tr = threadIdx.x >> 5, tc = threadIdx.x & 31;
#pragma unroll
  for (int p = 0; p < 4; ++p) {
    int r = p * 8 + tr;
    tile[r][tc] = src[(size_t)(rb * 32 + r) * C + cb * 32 + tc];
  }
  __syncthreads();
#pragma unroll
  for (int p = 0; p < 4; ++p) {
    int r = p * 8 + tr;
    dst[(size_t)(cb * 32 + r) * R + rb * 32 + tc] = f2bf(tile[tc][r]);
  }
}

__global__ __launch_bounds__(256) void tcast2_kernel(const float* __restrict__ Wqkv,
                                                     const float* __restrict__ Wout,
                                                     short* __restrict__ Wqt,
                                                     short* __restrict__ Wot) {
  __shared__ float tile[32][33];
  int cb = blockIdx.x, rb = blockIdx.y;
  if (cb < 96) tcast_body(Wqkv, Wqt, 1024, 3072, cb, rb, tile);
  else         tcast_body(Wout, Wot, 1024, 1024, cb - 96, rb, tile);
}

// ---------------- GEMM core (R5-verified): C[128x128] = A[M,K] @ Bt[N,K]^T ----------
__device__ __forceinline__ void gemm_stage(const short* __restrict__ A,
                                           const short* __restrict__ Bt, int K, int mb, int nb,
                                           int kk, short* As, short* Bs, int wave, int lane) {
#pragma unroll
  for (int i = 0; i < 2; ++i) {
    int sbase = i * 256 + wave * 64;
    int s = sbase + lane;
    int r = s >> 2;
    int cg = (s & 3) ^ ((s >> 3) & 3);   // chunk ^ ((row>>1)&3)
    g2l16(A + (size_t)(mb * 128 + r) * K + kk * 32 + cg * 8, As + sbase * 8);
    g2l16(Bt + (size_t)(nb * 128 + r) * K + kk * 32 + cg * 8, Bs + sbase * 8);
  }
}

__device__ __forceinline__ void gemm_compute(const short* As, const short* Bs, f32x4 acc[4][4],
                                             int quad, int l15, int wr, int wc) {
  short8 af[4], bq[4];
  int sw = quad ^ ((l15 >> 1) & 3);      // (row>>1)&3 == (l15>>1)&3 here
#pragma unroll
  for (int t = 0; t < 4; ++t) {
    af[t] = *(const short8*)(As + ((wr * 64 + t * 16 + l15) * 4 + sw) * 8);
    bq[t] = *(const short8*)(Bs + ((wc * 64 + t * 16 + l15) * 4 + sw) * 8);
  }
#pragma unroll
  for (int i = 0; i < 4; ++i)
#pragma unroll
    for (int j = 0; j < 4; ++j)
      acc[i][j] = __builtin_amdgcn_mfma_f32_16x16x32_bf16(af[i], bq[j], acc[i][j], 0, 0, 0);
}

__device__ __forceinline__ void gemm_core(const short* __restrict__ A, const short* __restrict__ Bt,
                                          int K, int mb, int nb, short* As, short* Bs,
                                          f32x4 acc[4][4]) {
  const int tid = threadIdx.x;
  const int wave = tid >> 6, lane = tid & 63;
  const int quad = lane >> 4, l15 = lane & 15;
  const int wr = wave >> 1, wc = wave & 1;
  f32x4 zero = {0.f, 0.f, 0.f, 0.f};
#pragma unroll
  for (int i = 0; i < 4; ++i)
#pragma unroll
    for (int j = 0; j < 4; ++j) acc[i][j] = zero;

  const int nK = K >> 5;
  gemm_stage(A, Bt, K, mb, nb, 0, As, Bs, wave, lane);
  __syncthreads();                              // vmcnt(0): tile 0 resident
  for (int kk = 0; kk < nK - 1; ++kk) {
    int cur = kk & 1;
    gemm_stage(A, Bt, K, mb, nb, kk + 1, As + (cur ^ 1) * 4096, Bs + (cur ^ 1) * 4096, wave, lane);
    gemm_compute(As + cur * 4096, Bs + cur * 4096, acc, quad, l15, wr, wc);
    __syncthreads();                            // drains prefetch + all waves' frag reads
  }
  gemm_compute(As + ((nK - 1) & 1) * 4096, Bs + ((nK - 1) & 1) * 4096, acc, quad, l15, wr, wc);
}

// ---------------- GEMM1: qkv = x @ Wqkv + bqkv; Q pre-scaled; V stored transposed ----
// R13: (a) XCD-chunked bijective block swizzle (1536%8==0): each XCD's L2 sees 8
// contiguous A-panels (2MB) instead of all 64. (b) LDS-staged coalesced epilogue:
// R12 counters showed WRITE 75MB vs 50MB payload + FETCH 72.7 vs 23MB inputs =
// ~50MB write-allocate RMW from partial-sector scalar stores. Stage bf16 tile in
// LDS (Cs[m][136] for Q/K, transposed Cs[n][136] + packed short4v for V), then
// each thread streams one 128B contiguous segment (8x16B stores) -> full sectors.
__global__ __launch_bounds__(256, 4) void gemm_qkv_kernel(
    const short* __restrict__ xb, const short* __restrict__ Wqt, const float* __restrict__ bqkv,
    short* __restrict__ Qb, short* __restrict__ Kb, short* __restrict__ Vt) {
  __shared__ alignas(16) short S[17408];   // loop: As=S[0..8191], Bs=S[8192..16383]; epi: Cs[128][136]
  f32x4 acc[4][4];
  int lid = blockIdx.y * 24 + blockIdx.x;  // 0..1535
  int nlid = (lid & 7) * 192 + (lid >> 3); // bijective chunked XCD swizzle
  int nb = nlid % 24, mb = nlid / 24;
  gemm_core(xb, Wqt, D_, mb, nb, S, S + 8192, acc);

  const int tid = threadIdx.x, wave = tid >> 6, lane = tid & 63;
  const int quad = lane >> 4, l15 = lane & 15;
  const int wr = wave >> 1, wc = wave & 1;
  int part = nb >> 3;

  __syncthreads();   // all waves done reading As/Bs before Cs overwrite

  if (part == 2) {
    // ---- V: stage transposed Cs[n][m] (rr-packed short4v), write t-contiguous ----
#pragma unroll
    for (int j = 0; j < 4; ++j) {
      int n = wc * 64 + j * 16 + l15;
      float bv = bqkv[nb * 128 + n];
#pragma unroll
      for (int i = 0; i < 4; ++i) {
        int m0 = wr * 64 + i * 16 + quad * 4;
        short4v pv;
#pragma unroll
        for (int rr = 0; rr < 4; ++rr) pv[rr] = f2bf(acc[i][j][rr] + bv);
        *(short4v*)(S + n * 136 + m0) = pv;
      }
    }
    __syncthreads();
    {
      int n = tid >> 1, hm = tid & 1;
      int hd = n & 63, h = ((nb & 7) << 1) + (n >> 6);
      int mg = mb * 128;
      int b = mg >> 11;
      int t0 = (mg & 2047) + hm * 64;
      short* dst = Vt + ((size_t)((b * H_ + h) * HD_ + hd)) * T_ + t0;
      const short* src = S + n * 136 + hm * 64;
#pragma unroll
      for (int k = 0; k < 8; ++k)
        *(short8*)(dst + k * 8) = *(const short8*)(src + k * 8);
    }
  } else {
    // ---- Q/K: stage Cs[m][n], write hd-contiguous 128B rows ----
    short* qk = (part == 0) ? Qb : Kb;
    float sc = (part == 0) ? QSCALE : 1.0f;   // fold attn scale*log2e into Q
#pragma unroll
    for (int j = 0; j < 4; ++j) {
      int n = wc * 64 + j * 16 + l15;
      float bv = bqkv[nb * 128 + n];
#pragma unroll
      for (int i = 0; i < 4; ++i) {
        int m0 = wr * 64 + i * 16 + quad * 4;
#pragma unroll
        for (int rr = 0; rr < 4; ++rr)
          S[(m0 + rr) * 136 + n] = f2bf((acc[i][j][rr] + bv) * sc);
      }
    }
    __syncthreads();
    {
      int m = tid >> 1, half = tid & 1;
      int mg = mb * 128 + m;
      int b = mg >> 11, t = mg & 2047;
      int h = ((nb & 7) << 1) + half;
      short* dst = qk + ((size_t)((b * H_ + h) * T_ + t)) * HD_;
      const short* src = S + m * 136 + half * 64;
#pragma unroll
      for (int k = 0; k < 8; ++k)
        *(short8*)(dst + k * 8) = *(const short8*)(src + k * 8);
    }
  }
}

// ---------------- GEMM2: out = attn_out @ Wout + bout (fp32 out) ----------------
// (fp32 rows: 64B per 16-lane group = full sectors already; left unchanged)
__global__ __launch_bounds__(256, 4) void gemm_out_kernel(
    const short* __restrict__ Ob, const short* __restrict__ Wot,
    const float* __restrict__ bout, float* __restrict__ out) {
  __shared__ alignas(16) short As[2 * 4096];
  __shared__ alignas(16) short Bs[2 * 4096];
  f32x4 acc[4][4];
  int nb = blockIdx.x, mb = blockIdx.y;
  gemm_core(Ob, Wot, D_, mb, nb, As, Bs, acc);

  const int tid = threadIdx.x, wave = tid >> 6, lane = tid & 63;
  const int quad = lane >> 4, l15 = lane & 15;
  const int wr = wave >> 1, wc = wave & 1;
#pragma unroll
  for (int j = 0; j < 4; ++j) {
    int n = nb * 128 + wc * 64 + j * 16 + l15;
    float bv = bout[n];
#pragma unroll
    for (int i = 0; i < 4; ++i) {
      int mrow = mb * 128 + wr * 64 + i * 16 + quad * 4;
#pragma unroll
      for (int rr = 0; rr < 4; ++rr) {
        out[(size_t)(mrow + rr) * D_ + n] = acc[i][j][rr] + bv;
      }
    }
  }
}

// ---------------- Flash attention, paired q-tiles, no-max softmax ----------------
// R5-exact (83.6us verified, VGPR 64, no spill). NOT XCD-swizzled: default mapping
// already co-locates same-bh blocks (stride-64 lids) on one XCD for K/V L2 reuse.
// K LDS: [key 0..127][chunk 0..7 ^ (key&7)]  (128B rows)
// V LDS: [hd 0..63][tchunk 0..15 ^ (hd&7)]   (256B rows)
__global__ __launch_bounds__(512, 2) void attn_kernel(
    const short* __restrict__ Qb, const short* __restrict__ Kb, const short* __restrict__ Vt,
    const short* __restrict__ PB, short* __restrict__ Ob) {
  __shared__ alignas(16) short Ks[2][8192];
  __shared__ alignas(16) short Vs[2][8192];
  __shared__ alignas(16) short Ps[8][512];   // per-wave P chunk 16q x 32k

  const int tid = threadIdx.x, wave = tid >> 6, lane = tid & 63;
  const int quad = lane >> 4, l15 = lane & 15;
  const int bh = blockIdx.x;
  const int pair = blockIdx.y;
  const int qa = pair, qb = 15 - pair;       // qa < qb always
  const int b = bh >> 4, h = bh & 15;

  // ---- stage Qa through Ks[0] and Qb through Vs[0] simultaneously (row-major) ----
  short8 aqA[2], aqB[2];
#pragma unroll
  for (int i = 0; i < 2; ++i) {
    int sbase = i * 512 + wave * 64;
    int s = sbase + lane;
    int r = s >> 3;
    int cg = (s & 7) ^ (r & 7);
    g2l16(Qb + ((size_t)bh * T_ + qa * 128 + r) * HD_ + cg * 8, &Ks[0][0] + sbase * 8);
    g2l16(Qb + ((size_t)bh * T_ + qb * 128 + r) * HD_ + cg * 8, &Vs[0][0] + sbase * 8);
  }
  __syncthreads();
  {
    int qrow = wave * 16 + l15;              // (qrow&7) == (l15&7)
#pragma unroll
    for (int c2 = 0; c2 < 2; ++c2) {
      int ch = (c2 * 4 + quad) ^ (l15 & 7);
      aqA[c2] = *(const short8*)(&Ks[0][0] + (qrow * 8 + ch) * 8);
      aqB[c2] = *(const short8*)(&Vs[0][0] + (qrow * 8 + ch) * 8);
    }
  }
  __syncthreads();   // all waves' Q frag reads done before KV staging overwrites

  f32x4 zero = {0.f, 0.f, 0.f, 0.f};
  f32x4 oA[4], oB[4];
  float liA[4], liB[4];
#pragma unroll
  for (int hj = 0; hj < 4; ++hj) { oA[hj] = zero; oB[hj] = zero; }
#pragma unroll
  for (int rr = 0; rr < 4; ++rr) { liA[rr] = 0.f; liB[rr] = 0.f; }

  const short* pbA = PB + ((size_t)(b * 136 + ((qa * (qa + 1)) >> 1)) * 512 + tid) * 32;
  const short* pbB = PB + ((size_t)(b * 136 + ((qb * (qb + 1)) >> 1)) * 512 + tid) * 32;
  short* pw = &Ps[wave][0];

  // stage K/V tile kt into buffer bufc (coalesced row-major + chunk swizzle)
  auto stage_kv = [&](int kt, int bufc) {
#pragma unroll
    for (int i = 0; i < 2; ++i) {
      int sbase = i * 512 + wave * 64;
      int s = sbase + lane;
      int rk = s >> 3, ck = (s & 7) ^ ((s >> 3) & 7);
      g2l16(Kb + ((size_t)bh * T_ + kt * 128 + rk) * HD_ + ck * 8, &Ks[bufc][0] + sbase * 8);
      int rv = s >> 4, cv = (s & 15) ^ ((s >> 4) & 7);
      g2l16(Vt + ((size_t)bh * HD_ + rv) * T_ + kt * 128 + cv * 8, &Vs[bufc][0] + sbase * 8);
    }
  };

  // full compute for k-tile kt out of buffer bufc (both q-tiles).
  // PB loaded per-half right at its C-init use: minimal live range.
  auto attn_step = [&](int kt, int bufc) {
    const short* Ksc = &Ks[bufc][0];
    const short* Vsc = &Vs[bufc][0];
    const int ks0 = quad ^ (l15 & 7), ks1 = ks0 ^ 4;
    const int vsw = l15 & 7;
#pragma unroll
    for (int tile = 0; tile < 2; ++tile) {
      if (tile == 1 && kt > qa) break;
      const short* pp = (tile == 0 ? pbB : pbA) + (size_t)kt * (512 * 32);
      const short8* aq = (tile == 0) ? aqB : aqA;
      f32x4* o = (tile == 0) ? oB : oA;
      float* li = (tile == 0) ? liB : liA;

#pragma unroll 1   // two sequential halves: peak sc live = 16 regs, not 32
      for (int half = 0; half < 2; ++half) {
        // ---- S(log2 domain) = sQ K^T + bias (bias as accumulator init) ----
        f32x4 sc[4];
#pragma unroll
        for (int j4 = 0; j4 < 2; ++j4) {
          short8 pb = *(const short8*)(pp + (half * 2 + j4) * 8);
#pragma unroll
          for (int tp = 0; tp < 2; ++tp)
#pragma unroll
            for (int rr = 0; rr < 4; ++rr) sc[j4 * 2 + tp][rr] = bf2f(pb[tp * 4 + rr]);
        }
#pragma unroll
        for (int tj = 0; tj < 4; ++tj) {
          int key = (half * 4 + tj) * 16 + l15;   // (key&7) == (l15&7)
          short8 bk0 = *(const short8*)(Ksc + (key * 8 + ks0) * 8);
          short8 bk1 = *(const short8*)(Ksc + (key * 8 + ks1) * 8);
          sc[tj] = __builtin_amdgcn_mfma_f32_16x16x32_bf16(aq[0], bk0, sc[tj], 0, 0, 0);
          sc[tj] = __builtin_amdgcn_mfma_f32_16x16x32_bf16(aq[1], bk1, sc[tj], 0, 0, 0);
        }

        // ---- p = exp2(s); per-lane li ----
#pragma unroll
        for (int tj = 0; tj < 4; ++tj)
#pragma unroll
          for (int rr = 0; rr < 4; ++rr) {
            float p = __builtin_amdgcn_exp2f(sc[tj][rr]);
            sc[tj][rr] = p;
            li[rr] += p;
          }

        // ---- O += P @ V  (P: C-layout -> A-layout via per-wave LDS chunk) ----
#pragma unroll
        for (int kc = 0; kc < 2; ++kc) {
          int kcc = half * 2 + kc;
#pragma unroll
          for (int tp = 0; tp < 2; ++tp) {
            int tj = kc * 2 + tp;
            int klc = tp * 16 + l15;
            int hi = (klc >> 3) * 16;
#pragma unroll
            for (int rr = 0; rr < 4; ++rr) {
              pw[(hi + quad * 4 + rr) * 8 + (klc & 7)] = f2bf_trunc(sc[tj][rr]);
            }
          }
          short8 ap = *(const short8*)(pw + (quad * 16 + l15) * 8);
#pragma unroll
          for (int hj = 0; hj < 4; ++hj) {
            int hd = hj * 16 + l15;            // (hd&7) == (l15&7)
            int tc = (kcc * 4 + quad) ^ vsw;
            short8 bv = *(const short8*)(Vsc + (hd * 16 + tc) * 8);
            o[hj] = __builtin_amdgcn_mfma_f32_16x16x32_bf16(ap, bv, o[hj], 0, 0, 0);
          }
        }
      }
    }
  };

  // ---- 2-phase main loop: prefetch kt+1 while computing kt ----
  stage_kv(0, 0);
  __syncthreads();                       // vmcnt(0): tile 0 resident
  for (int kt = 0; kt < qb; ++kt) {
    int cur = kt & 1;
    stage_kv(kt + 1, cur ^ 1);           // in flight across compute below
    attn_step(kt, cur);
    __syncthreads();                     // drains prefetch + all waves' LDS reads
  }
  attn_step(qb, qb & 1);

  // ---- single cross-lane li reduction (16 l15 lanes per row) ----
#pragma unroll
  for (int d = 1; d < 16; d <<= 1)
#pragma unroll
    for (int rr = 0; rr < 4; ++rr) {
      liA[rr] += __shfl_xor(liA[rr], d, 64);
      liB[rr] += __shfl_xor(liB[rr], d, 64);
    }

  // ---- epilogue: O / l -> Ob[B,T,D] bf16, both tiles ----
#pragma unroll
  for (int hj = 0; hj < 4; ++hj)
#pragma unroll
    for (int rr = 0; rr < 4; ++rr) {
      int qrow = wave * 16 + quad * 4 + rr;
      int dcol = h * 64 + hj * 16 + l15;
      Ob[((size_t)b * T_ + qa * 128 + qrow) * D_ + dcol] = f2bf(oA[hj][rr] / liA[rr]);
      Ob[((size_t)b * T_ + qb * 128 + qrow) * D_ + dcol] = f2bf(oB[hj][rr] / liB[rr]);
    }
}

// ---------------- host launcher ----------------
extern "C" void kernel_launch(void* const* d_in, const int* in_sizes, int n_in,
                              void* d_out, int out_size, void* d_ws, size_t ws_size,
                              hipStream_t stream) {
  const float* x    = (const float*)d_in[0];
  const float* bias = (const float*)d_in[1];
  const float* Wqkv = (const float*)d_in[2];
  const float* bqkv = (const float*)d_in[3];
  const float* Wout = (const float*)d_in[4];
  const float* bout = (const float*)d_in[5];
  float* out = (float*)d_out;
  char* ws = (char*)d_ws;

  // workspace layout (~93 MB, lifetime-aliased)
  short* xb   = (short*)(ws + 0);          // x bf16 [8192][1024]   (dead after gemm1)
  short* Ob   = (short*)(ws + 0);          // attn out [B,T,D] bf16 (aliases xb)
  short* Wqt  = (short*)(ws + 16777216);   // Wqkv^T bf16 [3072][1024]
  short* Wot  = (short*)(ws + 23068672);   // Wout^T bf16 [1024][1024]
  short* Qb   = (short*)(ws + 25165824);   // Q [BH][T][64] (pre-scaled)
  short* Kb   = (short*)(ws + 41943040);   // K [BH][T][64]
  short* Vt   = (short*)(ws + 58720256);   // V^T [BH][64][T] (written by gemm1)
  short* PB   = (short*)(ws + 75497472);   // bias C-frag tiles bf16, 17.8 MB

  prep_kernel<<<4640, 512, 0, stream>>>(x, xb, bias, PB);
  tcast2_kernel<<<dim3(128, 32), 256, 0, stream>>>(Wqkv, Wout, Wqt, Wot);
  gemm_qkv_kernel<<<dim3(24, 64), 256, 0, stream>>>(xb, Wqt, bqkv, Qb, Kb, Vt);
  attn_kernel<<<dim3(64, 8), 512, 0, stream>>>(Qb, Kb, Vt, PB, Ob);
  gemm_out_kernel<<<dim3(8, 64), 256, 0, stream>>>(Ob, Wot, bout, out);
}

// Round 16
// 326.709 us; speedup vs baseline: 1.0294x; 1.0294x over previous
//
#include <hip/hip_runtime.h>

typedef __attribute__((ext_vector_type(8))) short short8;
typedef __attribute__((ext_vector_type(4))) short short4v;
typedef __attribute__((ext_vector_type(4))) float f32x4;

#define B_  4
#define T_  2048
#define D_  1024
#define H_  16
#define HD_ 64

#define LOG2E 1.4426950408889634f
#define QSCALE 0.1803368801111243f   /* 0.125 * log2(e) */

__device__ __forceinline__ short f2bf(float f) {
  unsigned u = __builtin_bit_cast(unsigned, f);
  u = (u + 0x7FFFu + ((u >> 16) & 1u)) >> 16;
  return (short)u;
}
__device__ __forceinline__ short f2bf_trunc(float f) {   // 1-op pack for P (err <0.4%, biased low)
  return (short)(__builtin_bit_cast(unsigned, f) >> 16);
}
__device__ __forceinline__ float bf2f(short s) {
  unsigned u = ((unsigned)(unsigned short)s) << 16;
  return __builtin_bit_cast(float, u);
}

// async global->LDS, 16B per lane. lds ptr must be wave-uniform; HW adds lane*16.
__device__ __forceinline__ void g2l16(const void* g, void* l) {
  __builtin_amdgcn_global_load_lds((const __attribute__((address_space(1))) void*)g,
                                   (__attribute__((address_space(3))) void*)l, 16, 0, 0);
}

// ---------------- fused prep: x cast (0..4095) + bias->PB (4096..4639) +
// weight transpose-cast (4640..8735). One launch replaces three: all paths are
// memory-bound and independent; block-uniform branch; saves 2 launch gaps total.
__global__ __launch_bounds__(512) void prep_kernel(const float* __restrict__ x,
                                                   short* __restrict__ xb,
                                                   const float* __restrict__ bias,
                                                   short* __restrict__ PB,
                                                   const float* __restrict__ Wqkv,
                                                   const float* __restrict__ Wout,
                                                   short* __restrict__ Wqt,
                                                   short* __restrict__ Wot) {
  __shared__ float tile[32][33];
  int bid = blockIdx.x;
  if (bid < 4096) {
    // cast fp32 -> bf16, 512 thr x 4 elems
    int i = (bid * 512 + threadIdx.x) * 4;
    float4 v = *(const float4*)(x + i);
    short4v o;
    o.x = f2bf(v.x); o.y = f2bf(v.y); o.z = f2bf(v.z); o.w = f2bf(v.w);
    *(short4v*)(xb + i) = o;
    return;
  }
  if (bid < 4640) {
    // ---- bias -> C-fragment-layout bf16 tiles (mask + log2e folded) ----
    // PB[(b*136 + qt*(qt+1)/2 + kt)][tid 0..511][tj 0..7][rr 0..3]  (bf16)
    bid -= 4096;                     // 0..543
    int b = bid / 136, tidx = bid % 136;
    int qt = 0, base = 0;
    while (base + qt + 1 <= tidx) { base += qt + 1; ++qt; }
    int kt = tidx - base;
    int tid = threadIdx.x;
    int w = tid >> 6, lane = tid & 63, quad = lane >> 4, l15 = lane & 15;
    short vals[32];
#pragma unroll
    for (int tj = 0; tj < 8; ++tj)
#pragma unroll
      for (int rr = 0; rr < 4; ++rr) {
        int ql = w * 16 + quad * 4 + rr;
        int kl = tj * 16 + l15;
        float v = bias[((size_t)b * T_ + qt * 128 + ql) * T_ + kt * 128 + kl] * LOG2E;
        if (kt == qt && kl > ql) v = -1.0e9f;
        vals[tj * 4 + rr] = f2bf(v);
      }
    short* dst = PB + ((size_t)bid * 512 + tid) * 32;
#pragma unroll
    for (int j = 0; j < 4; ++j) *(short8*)(dst + j * 8) = *(const short8*)(vals + j * 8);
    return;
  }
  // ---- transpose-cast fp32 [R][C] -> bf16 [C][R] (512-thread variant) ----
  int t = bid - 4640;                // 0..4095
  int cb = t & 127, rb = t >> 7;
  const float* src; short* dst; int C;
  if (cb < 96) { src = Wqkv; dst = Wqt; C = 3072; }
  else         { src = Wout; dst = Wot; C = 1024; cb -= 96; }
  int tr = threadIdx.x >> 5, tc = threadIdx.x & 31;   // tr 0..15
#pragma unroll
  for (int p = 0; p < 2; ++p) {
    int r = p * 16 + tr;
    tile[r][tc] = src[(size_t)(rb * 32 + r) * C + cb * 32 + tc];
  }
  __syncthreads();
#pragma unroll
  for (int p = 0; p < 2; ++p) {
    int r = p * 16 + tr;
    dst[(size_t)(cb * 32 + r) * 1024 + rb * 32 + tc] = f2bf(tile[tc][r]);
  }
}

// ---------------- GEMM core (R5-verified): C[128x128] = A[M,K] @ Bt[N,K]^T ----------
__device__ __forceinline__ void gemm_stage(const short* __restrict__ A,
                                           const short* __restrict__ Bt, int K, int mb, int nb,
                                           int kk, short* As, short* Bs, int wave, int lane) {
#pragma unroll
  for (int i = 0; i < 2; ++i) {
    int sbase = i * 256 + wave * 64;
    int s = sbase + lane;
    int r = s >> 2;
    int cg = (s & 3) ^ ((s >> 3) & 3);   // chunk ^ ((row>>1)&3)
    g2l16(A + (size_t)(mb * 128 + r) * K + kk * 32 + cg * 8, As + sbase * 8);
    g2l16(Bt + (size_t)(nb * 128 + r) * K + kk * 32 + cg * 8, Bs + sbase * 8);
  }
}

__device__ __forceinline__ void gemm_compute(const short* As, const short* Bs, f32x4 acc[4][4],
                                             int quad, int l15, int wr, int wc) {
  short8 af[4], bq[4];
  int sw = quad ^ ((l15 >> 1) & 3);      // (row>>1)&3 == (l15>>1)&3 here
#pragma unroll
  for (int t = 0; t < 4; ++t) {
    af[t] = *(const short8*)(As + ((wr * 64 + t * 16 + l15) * 4 + sw) * 8);
    bq[t] = *(const short8*)(Bs + ((wc * 64 + t * 16 + l15) * 4 + sw) * 8);
  }
#pragma unroll
  for (int i = 0; i < 4; ++i)
#pragma unroll
    for (int j = 0; j < 4; ++j)
      acc[i][j] = __builtin_amdgcn_mfma_f32_16x16x32_bf16(af[i], bq[j], acc[i][j], 0, 0, 0);
}

__device__ __forceinline__ void gemm_core(const short* __restrict__ A, const short* __restrict__ Bt,
                                          int K, int mb, int nb, short* As, short* Bs,
                                          f32x4 acc[4][4]) {
  const int tid = threadIdx.x;
  const int wave = tid >> 6, lane = tid & 63;
  const int quad = lane >> 4, l15 = lane & 15;
  const int wr = wave >> 1, wc = wave & 1;
  f32x4 zero = {0.f, 0.f, 0.f, 0.f};
#pragma unroll
  for (int i = 0; i < 4; ++i)
#pragma unroll
    for (int j = 0; j < 4; ++j) acc[i][j] = zero;

  const int nK = K >> 5;
  gemm_stage(A, Bt, K, mb, nb, 0, As, Bs, wave, lane);
  __syncthreads();                              // vmcnt(0): tile 0 resident
  for (int kk = 0; kk < nK - 1; ++kk) {
    int cur = kk & 1;
    gemm_stage(A, Bt, K, mb, nb, kk + 1, As + (cur ^ 1) * 4096, Bs + (cur ^ 1) * 4096, wave, lane);
    gemm_compute(As + cur * 4096, Bs + cur * 4096, acc, quad, l15, wr, wc);
    __syncthreads();                            // drains prefetch + all waves' frag reads
  }
  gemm_compute(As + ((nK - 1) & 1) * 4096, Bs + ((nK - 1) & 1) * 4096, acc, quad, l15, wr, wc);
}

// ---------------- GEMM1: qkv = x @ Wqkv + bqkv; Q pre-scaled; V stored transposed ----
// R13-verified: XCD-chunked bijective swizzle + LDS-staged coalesced epilogue
// (full-sector 128B streams; eliminated ~50MB write-allocate RMW).
__global__ __launch_bounds__(256, 4) void gemm_qkv_kernel(
    const short* __restrict__ xb, const short* __restrict__ Wqt, const float* __restrict__ bqkv,
    short* __restrict__ Qb, short* __restrict__ Kb, short* __restrict__ Vt) {
  __shared__ alignas(16) short S[17408];   // loop: As=S[0..8191], Bs=S[8192..16383]; epi: Cs[128][136]
  f32x4 acc[4][4];
  int lid = blockIdx.y * 24 + blockIdx.x;  // 0..1535
  int nlid = (lid & 7) * 192 + (lid >> 3); // bijective chunked XCD swizzle
  int nb = nlid % 24, mb = nlid / 24;
  gemm_core(xb, Wqt, D_, mb, nb, S, S + 8192, acc);

  const int tid = threadIdx.x, wave = tid >> 6, lane = tid & 63;
  const int quad = lane >> 4, l15 = lane & 15;
  const int wr = wave >> 1, wc = wave & 1;
  int part = nb >> 3;

  __syncthreads();   // all waves done reading As/Bs before Cs overwrite

  if (part == 2) {
    // ---- V: stage transposed Cs[n][m] (rr-packed short4v), write t-contiguous ----
#pragma unroll
    for (int j = 0; j < 4; ++j) {
      int n = wc * 64 + j * 16 + l15;
      float bv = bqkv[nb * 128 + n];
#pragma unroll
      for (int i = 0; i < 4; ++i) {
        int m0 = wr * 64 + i * 16 + quad * 4;
        short4v pv;
#pragma unroll
        for (int rr = 0; rr < 4; ++rr) pv[rr] = f2bf(acc[i][j][rr] + bv);
        *(short4v*)(S + n * 136 + m0) = pv;
      }
    }
    __syncthreads();
    {
      int n = tid >> 1, hm = tid & 1;
      int hd = n & 63, h = ((nb & 7) << 1) + (n >> 6);
      int mg = mb * 128;
      int b = mg >> 11;
      int t0 = (mg & 2047) + hm * 64;
      short* dst = Vt + ((size_t)((b * H_ + h) * HD_ + hd)) * T_ + t0;
      const short* src = S + n * 136 + hm * 64;
#pragma unroll
      for (int k = 0; k < 8; ++k)
        *(short8*)(dst + k * 8) = *(const short8*)(src + k * 8);
    }
  } else {
    // ---- Q/K: stage Cs[m][n], write hd-contiguous 128B rows ----
    short* qk = (part == 0) ? Qb : Kb;
    float sc = (part == 0) ? QSCALE : 1.0f;   // fold attn scale*log2e into Q
#pragma unroll
    for (int j = 0; j < 4; ++j) {
      int n = wc * 64 + j * 16 + l15;
      float bv = bqkv[nb * 128 + n];
#pragma unroll
      for (int i = 0; i < 4; ++i) {
        int m0 = wr * 64 + i * 16 + quad * 4;
#pragma unroll
        for (int rr = 0; rr < 4; ++rr)
          S[(m0 + rr) * 136 + n] = f2bf((acc[i][j][rr] + bv) * sc);
      }
    }
    __syncthreads();
    {
      int m = tid >> 1, half = tid & 1;
      int mg = mb * 128 + m;
      int b = mg >> 11, t = mg & 2047;
      int h = ((nb & 7) << 1) + half;
      short* dst = qk + ((size_t)((b * H_ + h) * T_ + t)) * HD_;
      const short* src = S + m * 136 + half * 64;
#pragma unroll
      for (int k = 0; k < 8; ++k)
        *(short8*)(dst + k * 8) = *(const short8*)(src + k * 8);
    }
  }
}

// ---------------- GEMM2: out = attn_out @ Wout + bout (fp32 out) ----------------
// (fp32 rows: 64B per 16-lane group = full sectors already; left unchanged)
__global__ __launch_bounds__(256, 4) void gemm_out_kernel(
    const short* __restrict__ Ob, const short* __restrict__ Wot,
    const float* __restrict__ bout, float* __restrict__ out) {
  __shared__ alignas(16) short As[2 * 4096];
  __shared__ alignas(16) short Bs[2 * 4096];
  f32x4 acc[4][4];
  int nb = blockIdx.x, mb = blockIdx.y;
  gemm_core(Ob, Wot, D_, mb, nb, As, Bs, acc);

  const int tid = threadIdx.x, wave = tid >> 6, lane = tid & 63;
  const int quad = lane >> 4, l15 = lane & 15;
  const int wr = wave >> 1, wc = wave & 1;
#pragma unroll
  for (int j = 0; j < 4; ++j) {
    int n = nb * 128 + wc * 64 + j * 16 + l15;
    float bv = bout[n];
#pragma unroll
    for (int i = 0; i < 4; ++i) {
      int mrow = mb * 128 + wr * 64 + i * 16 + quad * 4;
#pragma unroll
      for (int rr = 0; rr < 4; ++rr) {
        out[(size_t)(mrow + rr) * D_ + n] = acc[i][j][rr] + bv;
      }
    }
  }
}

// ---------------- Flash attention, paired q-tiles, no-max softmax ----------------
// R5-exact (83.6-84us verified, VGPR 64, no spill).
// K LDS: [key 0..127][chunk 0..7 ^ (key&7)]  (128B rows)
// V LDS: [hd 0..63][tchunk 0..15 ^ (hd&7)]   (256B rows)
__global__ __launch_bounds__(512, 2) void attn_kernel(
    const short* __restrict__ Qb, const short* __restrict__ Kb, const short* __restrict__ Vt,
    const short* __restrict__ PB, short* __restrict__ Ob) {
  __shared__ alignas(16) short Ks[2][8192];
  __shared__ alignas(16) short Vs[2][8192];
  __shared__ alignas(16) short Ps[8][512];   // per-wave P chunk 16q x 32k

  const int tid = threadIdx.x, wave = tid >> 6, lane = tid & 63;
  const int quad = lane >> 4, l15 = lane & 15;
  const int bh = blockIdx.x;
  const int pair = blockIdx.y;
  const int qa = pair, qb = 15 - pair;       // qa < qb always
  const int b = bh >> 4, h = bh & 15;

  // ---- stage Qa through Ks[0] and Qb through Vs[0] simultaneously (row-major) ----
  short8 aqA[2], aqB[2];
#pragma unroll
  for (int i = 0; i < 2; ++i) {
    int sbase = i * 512 + wave * 64;
    int s = sbase + lane;
    int r = s >> 3;
    int cg = (s & 7) ^ (r & 7);
    g2l16(Qb + ((size_t)bh * T_ + qa * 128 + r) * HD_ + cg * 8, &Ks[0][0] + sbase * 8);
    g2l16(Qb + ((size_t)bh * T_ + qb * 128 + r) * HD_ + cg * 8, &Vs[0][0] + sbase * 8);
  }
  __syncthreads();
  {
    int qrow = wave * 16 + l15;              // (qrow&7) == (l15&7)
#pragma unroll
    for (int c2 = 0; c2 < 2; ++c2) {
      int ch = (c2 * 4 + quad) ^ (l15 & 7);
      aqA[c2] = *(const short8*)(&Ks[0][0] + (qrow * 8 + ch) * 8);
      aqB[c2] = *(const short8*)(&Vs[0][0] + (qrow * 8 + ch) * 8);
    }
  }
  __syncthreads();   // all waves' Q frag reads done before KV staging overwrites

  f32x4 zero = {0.f, 0.f, 0.f, 0.f};
  f32x4 oA[4], oB[4];
  float liA[4], liB[4];
#pragma unroll
  for (int hj = 0; hj < 4; ++hj) { oA[hj] = zero; oB[hj] = zero; }
#pragma unroll
  for (int rr = 0; rr < 4; ++rr) { liA[rr] = 0.f; liB[rr] = 0.f; }

  const short* pbA = PB + ((size_t)(b * 136 + ((qa * (qa + 1)) >> 1)) * 512 + tid) * 32;
  const short* pbB = PB + ((size_t)(b * 136 + ((qb * (qb + 1)) >> 1)) * 512 + tid) * 32;
  short* pw = &Ps[wave][0];

  // stage K/V tile kt into buffer bufc (coalesced row-major + chunk swizzle)
  auto stage_kv = [&](int kt, int bufc) {
#pragma unroll
    for (int i = 0; i < 2; ++i) {
      int sbase = i * 512 + wave * 64;
      int s = sbase + lane;
      int rk = s >> 3, ck = (s & 7) ^ ((s >> 3) & 7);
      g2l16(Kb + ((size_t)bh * T_ + kt * 128 + rk) * HD_ + ck * 8, &Ks[bufc][0] + sbase * 8);
      int rv = s >> 4, cv = (s & 15) ^ ((s >> 4) & 7);
      g2l16(Vt + ((size_t)bh * HD_ + rv) * T_ + kt * 128 + cv * 8, &Vs[bufc][0] + sbase * 8);
    }
  };

  // full compute for k-tile kt out of buffer bufc (both q-tiles).
  // PB loaded per-half right at its C-init use: minimal live range.
  auto attn_step = [&](int kt, int bufc) {
    const short* Ksc = &Ks[bufc][0];
    const short* Vsc = &Vs[bufc][0];
    const int ks0 = quad ^ (l15 & 7), ks1 = ks0 ^ 4;
    const int vsw = l15 & 7;
#pragma unroll
    for (int tile = 0; tile < 2; ++tile) {
      if (tile == 1 && kt > qa) break;
      const short* pp = (tile == 0 ? pbB : pbA) + (size_t)kt * (512 * 32);
      const short8* aq = (tile == 0) ? aqB : aqA;
      f32x4* o = (tile == 0) ? oB : oA;
      float* li = (tile == 0) ? liB : liA;

#pragma unroll 1   // two sequential halves: peak sc live = 16 regs, not 32
      for (int half = 0; half < 2; ++half) {
        // ---- S(log2 domain) = sQ K^T + bias (bias as accumulator init) ----
        f32x4 sc[4];
#pragma unroll
        for (int j4 = 0; j4 < 2; ++j4) {
          short8 pb = *(const short8*)(pp + (half * 2 + j4) * 8);
#pragma unroll
          for (int tp = 0; tp < 2; ++tp)
#pragma unroll
            for (int rr = 0; rr < 4; ++rr) sc[j4 * 2 + tp][rr] = bf2f(pb[tp * 4 + rr]);
        }
#pragma unroll
        for (int tj = 0; tj < 4; ++tj) {
          int key = (half * 4 + tj) * 16 + l15;   // (key&7) == (l15&7)
          short8 bk0 = *(const short8*)(Ksc + (key * 8 + ks0) * 8);
          short8 bk1 = *(const short8*)(Ksc + (key * 8 + ks1) * 8);
          sc[tj] = __builtin_amdgcn_mfma_f32_16x16x32_bf16(aq[0], bk0, sc[tj], 0, 0, 0);
          sc[tj] = __builtin_amdgcn_mfma_f32_16x16x32_bf16(aq[1], bk1, sc[tj], 0, 0, 0);
        }

        // ---- p = exp2(s); per-lane li ----
#pragma unroll
        for (int tj = 0; tj < 4; ++tj)
#pragma unroll
          for (int rr = 0; rr < 4; ++rr) {
            float p = __builtin_amdgcn_exp2f(sc[tj][rr]);
            sc[tj][rr] = p;
            li[rr] += p;
          }

        // ---- O += P @ V  (P: C-layout -> A-layout via per-wave LDS chunk) ----
#pragma unroll
        for (int kc = 0; kc < 2; ++kc) {
          int kcc = half * 2 + kc;
#pragma unroll
          for (int tp = 0; tp < 2; ++tp) {
            int tj = kc * 2 + tp;
            int klc = tp * 16 + l15;
            int hi = (klc >> 3) * 16;
#pragma unroll
            for (int rr = 0; rr < 4; ++rr) {
              pw[(hi + quad * 4 + rr) * 8 + (klc & 7)] = f2bf_trunc(sc[tj][rr]);
            }
          }
          short8 ap = *(const short8*)(pw + (quad * 16 + l15) * 8);
#pragma unroll
          for (int hj = 0; hj < 4; ++hj) {
            int hd = hj * 16 + l15;            // (hd&7) == (l15&7)
            int tc = (kcc * 4 + quad) ^ vsw;
            short8 bv = *(const short8*)(Vsc + (hd * 16 + tc) * 8);
            o[hj] = __builtin_amdgcn_mfma_f32_16x16x32_bf16(ap, bv, o[hj], 0, 0, 0);
          }
        }
      }
    }
  };

  // ---- 2-phase main loop: prefetch kt+1 while computing kt ----
  stage_kv(0, 0);
  __syncthreads();                       // vmcnt(0): tile 0 resident
  for (int kt = 0; kt < qb; ++kt) {
    int cur = kt & 1;
    stage_kv(kt + 1, cur ^ 1);           // in flight across compute below
    attn_step(kt, cur);
    __syncthreads();                     // drains prefetch + all waves' LDS reads
  }
  attn_step(qb, qb & 1);

  // ---- single cross-lane li reduction (16 l15 lanes per row) ----
#pragma unroll
  for (int d = 1; d < 16; d <<= 1)
#pragma unroll
    for (int rr = 0; rr < 4; ++rr) {
      liA[rr] += __shfl_xor(liA[rr], d, 64);
      liB[rr] += __shfl_xor(liB[rr], d, 64);
    }

  // ---- epilogue: O / l -> Ob[B,T,D] bf16, both tiles ----
#pragma unroll
  for (int hj = 0; hj < 4; ++hj)
#pragma unroll
    for (int rr = 0; rr < 4; ++rr) {
      int qrow = wave * 16 + quad * 4 + rr;
      int dcol = h * 64 + hj * 16 + l15;
      Ob[((size_t)b * T_ + qa * 128 + qrow) * D_ + dcol] = f2bf(oA[hj][rr] / liA[rr]);
      Ob[((size_t)b * T_ + qb * 128 + qrow) * D_ + dcol] = f2bf(oB[hj][rr] / liB[rr]);
    }
}

// ---------------- host launcher ----------------
extern "C" void kernel_launch(void* const* d_in, const int* in_sizes, int n_in,
                              void* d_out, int out_size, void* d_ws, size_t ws_size,
                              hipStream_t stream) {
  const float* x    = (const float*)d_in[0];
  const float* bias = (const float*)d_in[1];
  const float* Wqkv = (const float*)d_in[2];
  const float* bqkv = (const float*)d_in[3];
  const float* Wout = (const float*)d_in[4];
  const float* bout = (const float*)d_in[5];
  float* out = (float*)d_out;
  char* ws = (char*)d_ws;

  // workspace layout (~93 MB, lifetime-aliased)
  short* xb   = (short*)(ws + 0);          // x bf16 [8192][1024]   (dead after gemm1)
  short* Ob   = (short*)(ws + 0);          // attn out [B,T,D] bf16 (aliases xb)
  short* Wqt  = (short*)(ws + 16777216);   // Wqkv^T bf16 [3072][1024]
  short* Wot  = (short*)(ws + 23068672);   // Wout^T bf16 [1024][1024]
  short* Qb   = (short*)(ws + 25165824);   // Q [BH][T][64] (pre-scaled)
  short* Kb   = (short*)(ws + 41943040);   // K [BH][T][64]
  short* Vt   = (short*)(ws + 58720256);   // V^T [BH][64][T] (written by gemm1)
  short* PB   = (short*)(ws + 75497472);   // bias C-frag tiles bf16, 17.8 MB

  prep_kernel<<<8736, 512, 0, stream>>>(x, xb, bias, PB, Wqkv, Wout, Wqt, Wot);
  gemm_qkv_kernel<<<dim3(24, 64), 256, 0, stream>>>(xb, Wqt, bqkv, Qb, Kb, Vt);
  attn_kernel<<<dim3(64, 8), 512, 0, stream>>>(Qb, Kb, Vt, PB, Ob);
  gemm_out_kernel<<<dim3(8, 64), 256, 0, stream>>>(Ob, Wot, bout, out);
}